// Round 4
// baseline (102.817 us; speedup 1.0000x reference)
//
#include <hip/hip_runtime.h>

// Problem constants: N1=N2=512, C=256, H=512. Inputs/outputs fp32.
// M[i,j] = b2 + sum_h relu(hx[i,h] + hy[j,h] + b1[h]) * w2[h]
//   hx = (X @ W_sr.T) @ W1x.T, hy = (Y @ W_tg.T) @ W1y.T + b1.
//
// All stages move f16 data and accumulate fp32 via v_dot2_f32_f16.
// R3 lesson: grid.sync ~35us on gfx950 -- separate launches are cheaper.
// R1 lesson: cap unrolls (full unroll -> 256 VGPR + scratch spills).
// R5 lesson: both GEMMs LDS-pipe-bound; big per-thread tiles, 1 block/CU.
// R6: reduce8 folded into atomicAdd epilogue (out prefilled with b2);
//     register double-buffered GEMM staging. 105.4 -> 98.6us.
// R8: full-K LDS staging, ONE barrier per GEMM. 98.6 -> 94.9us. Confirmed
//     ~80us harness poison-fill floor; our pipeline ~14.7us.
// R9 (this round): fuse gemm1+gemm2 into one 512-block kernel with an
//   in-kernel producer->consumer handshake:
//   - 52KB LDS/block => capacity 3 blocks/CU => all 512 blocks co-resident
//     for ANY dispatch order => spin-wait deadlock-free (no XCD assumption).
//   - producer: store tile, __syncthreads (vmcnt drain), agent-RELEASE
//     flag store (buffer_wbl2 -> LLC). consumer: stage B (W1) FIRST
//     (overlaps producers), poll 8 slab flags relaxed, ONE agent-ACQUIRE
//     fence (buffer_inv), stage A, compute. Bounded spin: hang->wrong,
//     never timeout.

typedef _Float16 h2 __attribute__((ext_vector_type(2)));
typedef _Float16 h4 __attribute__((ext_vector_type(4)));
typedef _Float16 h8 __attribute__((ext_vector_type(8)));

#define SLAB_MAGIC 0x00C0FFEE

// ---------------------------------------------------------------------------
// Fused GEMM stage: producers (bid<256) compute Xp = X @ W_sr.T (z=0) /
// Yp = Y @ W_tg.T (z=1), BM=32 BN=32, full K in LDS, and prefill out=b2.
// Consumers (bid>=256) compute hx = Xp @ W1x.T / hy = Yp @ W1y.T + b1,
// BM=32 BN=64, full K in LDS. Per-(slab,z) flag handshake, agent scope.
// ---------------------------------------------------------------------------
__global__ __launch_bounds__(128) void fused_gemm12(
    const float* __restrict__ X, const float* __restrict__ Y,
    const float* __restrict__ Wsr, const float* __restrict__ Wtg,
    const float* __restrict__ W1, const float* __restrict__ b1,
    const float* __restrict__ b2,
    _Float16* __restrict__ Xp, _Float16* __restrict__ Yp,
    _Float16* __restrict__ hx, _Float16* __restrict__ hy,
    float* __restrict__ out, int* __restrict__ flags)
{
    __shared__ _Float16 As2[128 * 72];    // [kp][2m], stride 72 halfs
    __shared__ _Float16 Bs2[128 * 136];   // consumer B; producer uses 72-stride

    const int bid = blockIdx.x;
    const int t   = threadIdx.x;

    if (bid < 256) {
        // ================= producer: gemm1 tile =================
        const int x = bid & 15, y = (bid >> 4) & 7, z = bid >> 7;
        const float* A = z ? Y : X;
        const float* B = z ? Wtg : Wsr;
        _Float16* Cc   = z ? Yp : Xp;
        const int m0 = x * 32;
        const int n0 = y * 32;
        const int ti = t >> 4;   // 0..7
        const int tj = t & 15;   // 0..15

        // out <- b2 (1024 floats per producer block), re-runs every replay.
        {
            const float bb = b2[0];
            float4 f = {bb, bb, bb, bb};
            float* o = out + bid * 1024 + t * 8;
            *(float4*)o = f;
            *(float4*)(o + 4) = f;
        }

        // Stage ALL of K (8 virtual tiles, proven pair-major mapping).
        #pragma unroll 4
        for (int r = 0; r < 8; r++) {
            const int kt = r * 32;
            #pragma unroll
            for (int s = 0; s < 2; s++) {
                const int id  = t + s * 128;
                const int m   = id >> 3;
                const int k4  = (id & 7) * 4;
                const int kp0 = r * 16 + (k4 >> 1);
                float4 va = *(const float4*)&A[(m0 + m) * 256 + kt + k4];
                h2 alo = {(_Float16)va.x, (_Float16)va.y};
                h2 ahi = {(_Float16)va.z, (_Float16)va.w};
                *(h2*)&As2[kp0 * 72 + 2 * m]       = alo;
                *(h2*)&As2[(kp0 + 1) * 72 + 2 * m] = ahi;
                float4 vb = *(const float4*)&B[(n0 + m) * 256 + kt + k4];
                h2 blo = {(_Float16)vb.x, (_Float16)vb.y};
                h2 bhi = {(_Float16)vb.z, (_Float16)vb.w};
                *(h2*)&Bs2[kp0 * 72 + 2 * m]       = blo;
                *(h2*)&Bs2[(kp0 + 1) * 72 + 2 * m] = bhi;
            }
        }
        __syncthreads();

        float acc[4][2] = {};
        #pragma unroll 8
        for (int kp = 0; kp < 128; kp++) {
            h8 a = *(const h8*)&As2[kp * 72 + 8 * ti];
            h4 b = *(const h4*)&Bs2[kp * 72 + 4 * tj];
            const h2* ap = (const h2*)&a;
            const h2* bp = (const h2*)&b;
            #pragma unroll
            for (int mi = 0; mi < 4; mi++)
                #pragma unroll
                for (int nj = 0; nj < 2; nj++)
                    acc[mi][nj] = __builtin_amdgcn_fdot2(ap[mi], bp[nj],
                                                         acc[mi][nj], false);
        }

        #pragma unroll
        for (int mi = 0; mi < 4; mi++) {
            const int m = m0 + 4 * ti + mi;
            h2 r = {(_Float16)acc[mi][0], (_Float16)acc[mi][1]};
            *(h2*)&Cc[m * 256 + n0 + 2 * tj] = r;
        }

        // Drain this block's stores (syncthreads implies vmcnt(0) per thread),
        // then publish: agent-scope release pushes dirty L2 lines to LLC.
        __syncthreads();
        if (t == 0) {
            __hip_atomic_store(&flags[(x * 2 + z) * 8 + y], SLAB_MAGIC,
                               __ATOMIC_RELEASE, __HIP_MEMORY_SCOPE_AGENT);
        }
    } else {
        // ================= consumer: gemm2 tile =================
        const int cid = bid - 256;
        const int x = cid & 15, y = (cid >> 4) & 7, z = cid >> 7;
        const _Float16* A = z ? Yp : Xp;
        const float* B    = W1 + (z ? 256 : 0);
        _Float16* Cc      = z ? hy : hx;
        const float* bias = z ? b1 : nullptr;
        const int m0 = x * 32;
        const int n0 = y * 64;
        const int ti = t >> 4;   // 0..7
        const int tj = t & 15;   // 0..15

        // Stage B (W1) FIRST -- independent of producers, overlaps them.
        #pragma unroll 4
        for (int r = 0; r < 8; r++) {
            const int kt = r * 32;
            #pragma unroll
            for (int s = 0; s < 4; s++) {
                const int id  = t + s * 128;
                const int n   = id >> 3;
                const int k4  = (id & 7) * 4;
                const int kp0 = r * 16 + (k4 >> 1);
                float4 v = *(const float4*)&B[(n0 + n) * 512 + kt + k4];
                h2 lo = {(_Float16)v.x, (_Float16)v.y};
                h2 hi = {(_Float16)v.z, (_Float16)v.w};
                *(h2*)&Bs2[kp0 * 136 + 2 * n]       = lo;
                *(h2*)&Bs2[(kp0 + 1) * 136 + 2 * n] = hi;
            }
        }

        // Wait for this slab's 8 producers (bounded spin -- never hangs).
        if (t < 8) {
            int guard = 0;
            while (__hip_atomic_load(&flags[(x * 2 + z) * 8 + t],
                                     __ATOMIC_RELAXED,
                                     __HIP_MEMORY_SCOPE_AGENT) != SLAB_MAGIC) {
                __builtin_amdgcn_s_sleep(2);
                if (++guard > (1 << 20)) break;
            }
        }
        __syncthreads();
        // Acquire: invalidate stale local-L2 lines so Xp/Yp reads see LLC.
        __builtin_amdgcn_fence(__ATOMIC_ACQUIRE, "agent");

        // Stage A (Xp/Yp f16).
        #pragma unroll 4
        for (int r = 0; r < 8; r++) {
            const int kt  = r * 32;
            const int m   = t >> 2;
            const int k8  = (t & 3) * 8;
            const int kp0 = r * 16 + (k8 >> 1);
            h8 v = *(const h8*)&A[(m0 + m) * 256 + kt + k8];
            #pragma unroll
            for (int i = 0; i < 4; i++) {
                h2 p = {v[2 * i], v[2 * i + 1]};
                *(h2*)&As2[(kp0 + i) * 72 + 2 * m] = p;
            }
        }
        __syncthreads();

        float acc[4][4] = {};
        #pragma unroll 8
        for (int kp = 0; kp < 128; kp++) {
            h8 a = *(const h8*)&As2[kp * 72 + 8 * ti];
            h8 b = *(const h8*)&Bs2[kp * 136 + 8 * tj];
            const h2* ap = (const h2*)&a;
            const h2* bp = (const h2*)&b;
            #pragma unroll
            for (int mi = 0; mi < 4; mi++)
                #pragma unroll
                for (int nj = 0; nj < 4; nj++)
                    acc[mi][nj] = __builtin_amdgcn_fdot2(ap[mi], bp[nj],
                                                         acc[mi][nj], false);
        }

        float4 bv = {0.f, 0.f, 0.f, 0.f};
        if (bias) bv = *(const float4*)&bias[n0 + 4 * tj];
        #pragma unroll
        for (int mi = 0; mi < 4; mi++) {
            const int m = m0 + 4 * ti + mi;
            h4 r = {(_Float16)(acc[mi][0] + bv.x),
                    (_Float16)(acc[mi][1] + bv.y),
                    (_Float16)(acc[mi][2] + bv.z),
                    (_Float16)(acc[mi][3] + bv.w)};
            *(h4*)&Cc[m * 512 + n0 + 4 * tj] = r;
        }
    }
}

// ---------------------------------------------------------------------------
// Core: out[i,j] += sum_{h in 64-slab s} relu(hx[i,h]+hy[j,h])*w2[h]
// grid (8,8,8) = 512 blocks (2/CU), 256 threads, 4x4 register tile.
// f16 operands, v_dot2_f32_f16 accumulate. f32 atomicAdd epilogue into
// out (pre-filled with b2 by the fused kernel's producers).
// (proven R4/R5 body -- LDS ~6.9K cy vs VALU ~6.1K cy per CU, balanced)
// ---------------------------------------------------------------------------
__global__ __launch_bounds__(256) void affinity_core(
    const _Float16* __restrict__ hx, const _Float16* __restrict__ hy,
    const float* __restrict__ w2, float* __restrict__ out)
{
    __shared__ __align__(16) _Float16 xs[64 * 72];
    __shared__ __align__(16) _Float16 ys[64 * 72];
    __shared__ __align__(16) _Float16 ws2[64];

    const int t  = threadIdx.x;
    const int i0 = blockIdx.x * 64;
    const int j0 = blockIdx.y * 64;
    const int h0 = blockIdx.z * 64;
    const int ti = t / 16;
    const int tj = t % 16;

    #pragma unroll
    for (int s = 0; s < 2; s++) {
        const int id = t + s * 256;
        const int r  = id >> 3;
        const int c8 = (id & 7) * 8;
        *(float4*)&xs[r * 72 + c8] = *(const float4*)&hx[(i0 + r) * 512 + h0 + c8];
        *(float4*)&ys[r * 72 + c8] = *(const float4*)&hy[(j0 + r) * 512 + h0 + c8];
    }
    if (t < 64) ws2[t] = (_Float16)w2[h0 + t];
    __syncthreads();

    float acc[4][4] = {};
    const _Float16* xr = xs + ti * 72;
    const _Float16* yr = ys + tj * 72;
    const h2 hz = {(_Float16)0.f, (_Float16)0.f};

    #pragma unroll 2
    for (int g = 0; g < 8; g++) {
        const int ho = g * 8;
        h8 w = *(const h8*)&ws2[ho];
        h8 x[4], y[4];
        #pragma unroll
        for (int m = 0; m < 4; m++) x[m] = *(const h8*)&xr[m * (16 * 72) + ho];
        #pragma unroll
        for (int n = 0; n < 4; n++) y[n] = *(const h8*)&yr[n * (16 * 72) + ho];
        const h2* wp = (const h2*)&w;
        #pragma unroll
        for (int m = 0; m < 4; m++) {
            const h2* xp = (const h2*)&x[m];
            #pragma unroll
            for (int n = 0; n < 4; n++) {
                const h2* yp = (const h2*)&y[n];
                float a = acc[m][n];
                #pragma unroll
                for (int p = 0; p < 4; p++) {
                    h2 s = xp[p] + yp[p];                           // v_pk_add_f16
                    s = __builtin_elementwise_max(s, hz);           // v_pk_max_f16
                    a = __builtin_amdgcn_fdot2(s, wp[p], a, false); // v_dot2_f32_f16
                }
                acc[m][n] = a;
            }
        }
    }

    // Atomic f32 epilogue: 8-way contention per address (one per h-slab).
    #pragma unroll
    for (int m = 0; m < 4; m++) {
        #pragma unroll
        for (int n = 0; n < 4; n++) {
            atomicAdd(&out[(i0 + ti + 16 * m) * 512 + (j0 + tj + 16 * n)],
                      acc[m][n]);
        }
    }
}

extern "C" void kernel_launch(void* const* d_in, const int* in_sizes, int n_in,
                              void* d_out, int out_size, void* d_ws, size_t ws_size,
                              hipStream_t stream) {
    const float* X    = (const float*)d_in[0];  // 512x256
    const float* Y    = (const float*)d_in[1];  // 512x256
    const float* W_sr = (const float*)d_in[2];  // 256x256
    const float* W_tg = (const float*)d_in[3];  // 256x256
    const float* W1   = (const float*)d_in[4];  // 512x512 (H x 2C)
    const float* b1   = (const float*)d_in[5];  // 512
    const float* w2   = (const float*)d_in[6];  // 1x512
    const float* b2   = (const float*)d_in[7];  // 1

    float* ws = (float*)d_ws;
    _Float16* Xp = (_Float16*)ws;               // 512x256 f16
    _Float16* Yp = (_Float16*)(ws + 65536);     // 512x256 f16
    _Float16* hx = (_Float16*)(ws + 131072);    // 512x512 f16
    _Float16* hy = (_Float16*)(ws + 262144);    // 512x512 f16
    int* flags   = (int*)(ws + 393216);         // 256 ints (poisoned != MAGIC)
    float* out = (float*)d_out;

    // Stage 1+2 fused: producers (Xp/Yp + out prefill) and consumers (hx/hy)
    // co-resident; per-slab flag handshake, agent-scope release/acquire.
    fused_gemm12<<<512, 128, 0, stream>>>(
        X, Y, W_sr, W_tg, W1, b1, b2, Xp, Yp, hx, hy, out, flags);
    // Stage 3: h-split relu reduction, atomic f32 accumulate into out
    affinity_core<<<dim3(8, 8, 8), 256, 0, stream>>>(hx, hy, w2, out);
}

// Round 5
// 95.840 us; speedup vs baseline: 1.0728x; 1.0728x over previous
//
#include <hip/hip_runtime.h>

// Problem constants: N1=N2=512, C=256, H=512. Inputs/outputs fp32.
// M[i,j] = b2 + sum_h relu(hx[i,h] + hy[j,h] + b1[h]) * w2[h]
//   hx = (X @ W_sr.T) @ W1x.T, hy = (Y @ W_tg.T) @ W1y.T + b1.
//
// All stages move f16 data and accumulate fp32 via v_dot2_f32_f16.
// R3: grid.sync ~35us on gfx950 -- separate launches cheaper.
// R5: GEMMs LDS-pipe-bound; big per-thread tiles, 1 block/CU.
// R6: reduce8 -> atomicAdd epilogue (out prefilled with b2). 105.4->98.6.
// R8: full-K LDS staging, ONE barrier per GEMM. 98.6->94.9. ~80us harness
//     poison-fill floor confirmed; controllable pipeline ~14.7us.
// R9: fused gemm1+gemm2 with RELEASE/ACQUIRE agent fences: PASSED but
//     +7.9us -- 512 TCC-wide wbl2/inv ops cost ~10us. Lesson: never use
//     agent release/acquire fences at block granularity on gfx950.
// R10 (this round): same fusion, ZERO fences. Producers write Xp/Yp via
//   relaxed agent-scope atomic stores (write-through to LLC, no L2 flush);
//   __syncthreads drains vmcnt; relaxed flag store publishes. Consumers
//   poll flags relaxed and read Xp/Yp via relaxed agent-scope atomic
//   loads (bypass stale local L2) -- no buffer_inv anywhere. Correctness
//   of the handshake itself was proven by R9 (passed); the atomicAdd
//   epilogue proves per-access agent coherence is cheap.

typedef _Float16 h2 __attribute__((ext_vector_type(2)));
typedef _Float16 h4 __attribute__((ext_vector_type(4)));
typedef _Float16 h8 __attribute__((ext_vector_type(8)));

#define SLAB_MAGIC 0x00C0FFEE

// ---------------------------------------------------------------------------
// Fused GEMM stage: producers (bid<256) compute Xp = X @ W_sr.T (z=0) /
// Yp = Y @ W_tg.T (z=1), BM=32 BN=32, full K in LDS, and prefill out=b2.
// Consumers (bid>=256) compute hx = Xp @ W1x.T / hy = Yp @ W1y.T + b1,
// BM=32 BN=64, full K in LDS. Per-(slab,z) flags; relaxed agent atomics.
// 53KB LDS => 3 blocks/CU capacity => all 512 blocks co-resident for any
// dispatch order => spin deadlock-free. Spin is bounded regardless.
// ---------------------------------------------------------------------------
__global__ __launch_bounds__(128) void fused_gemm12(
    const float* __restrict__ X, const float* __restrict__ Y,
    const float* __restrict__ Wsr, const float* __restrict__ Wtg,
    const float* __restrict__ W1, const float* __restrict__ b1,
    const float* __restrict__ b2,
    _Float16* __restrict__ Xp, _Float16* __restrict__ Yp,
    _Float16* __restrict__ hx, _Float16* __restrict__ hy,
    float* __restrict__ out, int* __restrict__ flags)
{
    __shared__ _Float16 As2[128 * 72];    // [kp][2m], stride 72 halfs
    __shared__ _Float16 Bs2[128 * 136];   // consumer B; producer uses 72-stride

    const int bid = blockIdx.x;
    const int t   = threadIdx.x;

    if (bid < 256) {
        // ================= producer: gemm1 tile =================
        const int x = bid & 15, y = (bid >> 4) & 7, z = bid >> 7;
        const float* A = z ? Y : X;
        const float* B = z ? Wtg : Wsr;
        _Float16* Cc   = z ? Yp : Xp;
        const int m0 = x * 32;
        const int n0 = y * 32;
        const int ti = t >> 4;   // 0..7
        const int tj = t & 15;   // 0..15

        // out <- b2 (1024 floats per producer block), re-runs every replay.
        {
            const float bb = b2[0];
            float4 f = {bb, bb, bb, bb};
            float* o = out + bid * 1024 + t * 8;
            *(float4*)o = f;
            *(float4*)(o + 4) = f;
        }

        // Stage ALL of K (8 virtual tiles, proven pair-major mapping).
        #pragma unroll 4
        for (int r = 0; r < 8; r++) {
            const int kt = r * 32;
            #pragma unroll
            for (int s = 0; s < 2; s++) {
                const int id  = t + s * 128;
                const int m   = id >> 3;
                const int k4  = (id & 7) * 4;
                const int kp0 = r * 16 + (k4 >> 1);
                float4 va = *(const float4*)&A[(m0 + m) * 256 + kt + k4];
                h2 alo = {(_Float16)va.x, (_Float16)va.y};
                h2 ahi = {(_Float16)va.z, (_Float16)va.w};
                *(h2*)&As2[kp0 * 72 + 2 * m]       = alo;
                *(h2*)&As2[(kp0 + 1) * 72 + 2 * m] = ahi;
                float4 vb = *(const float4*)&B[(n0 + m) * 256 + kt + k4];
                h2 blo = {(_Float16)vb.x, (_Float16)vb.y};
                h2 bhi = {(_Float16)vb.z, (_Float16)vb.w};
                *(h2*)&Bs2[kp0 * 72 + 2 * m]       = blo;
                *(h2*)&Bs2[(kp0 + 1) * 72 + 2 * m] = bhi;
            }
        }
        __syncthreads();

        float acc[4][2] = {};
        #pragma unroll 8
        for (int kp = 0; kp < 128; kp++) {
            h8 a = *(const h8*)&As2[kp * 72 + 8 * ti];
            h4 b = *(const h4*)&Bs2[kp * 72 + 4 * tj];
            const h2* ap = (const h2*)&a;
            const h2* bp = (const h2*)&b;
            #pragma unroll
            for (int mi = 0; mi < 4; mi++)
                #pragma unroll
                for (int nj = 0; nj < 2; nj++)
                    acc[mi][nj] = __builtin_amdgcn_fdot2(ap[mi], bp[nj],
                                                         acc[mi][nj], false);
        }

        // Coherent write-through stores (no L2 flush needed later).
        #pragma unroll
        for (int mi = 0; mi < 4; mi++) {
            const int m = m0 + 4 * ti + mi;
            h2 r = {(_Float16)acc[mi][0], (_Float16)acc[mi][1]};
            unsigned int u;
            __builtin_memcpy(&u, &r, 4);
            __hip_atomic_store((unsigned int*)&Cc[m * 256 + n0 + 2 * tj], u,
                               __ATOMIC_RELAXED, __HIP_MEMORY_SCOPE_AGENT);
        }

        // __syncthreads drains every wave's vmcnt (compiler emits
        // s_waitcnt vmcnt(0) before s_barrier) => all coherent stores are
        // globally visible; then a RELAXED flag store publishes. No wbl2.
        __syncthreads();
        if (t == 0) {
            __hip_atomic_store(&flags[(x * 2 + z) * 8 + y], SLAB_MAGIC,
                               __ATOMIC_RELAXED, __HIP_MEMORY_SCOPE_AGENT);
        }
    } else {
        // ================= consumer: gemm2 tile =================
        const int cid = bid - 256;
        const int x = cid & 15, y = (cid >> 4) & 7, z = cid >> 7;
        const _Float16* A = z ? Yp : Xp;
        const float* B    = W1 + (z ? 256 : 0);
        _Float16* Cc      = z ? hy : hx;
        const float* bias = z ? b1 : nullptr;
        const int m0 = x * 32;
        const int n0 = y * 64;
        const int ti = t >> 4;   // 0..7
        const int tj = t & 15;   // 0..15

        // Stage B (W1) FIRST -- independent of producers, overlaps them.
        #pragma unroll 4
        for (int r = 0; r < 8; r++) {
            const int kt = r * 32;
            #pragma unroll
            for (int s = 0; s < 4; s++) {
                const int id  = t + s * 128;
                const int n   = id >> 3;
                const int k4  = (id & 7) * 4;
                const int kp0 = r * 16 + (k4 >> 1);
                float4 v = *(const float4*)&B[(n0 + n) * 512 + kt + k4];
                h2 lo = {(_Float16)v.x, (_Float16)v.y};
                h2 hi = {(_Float16)v.z, (_Float16)v.w};
                *(h2*)&Bs2[kp0 * 136 + 2 * n]       = lo;
                *(h2*)&Bs2[(kp0 + 1) * 136 + 2 * n] = hi;
            }
        }

        // Wait for this slab's 8 producers (bounded spin -- never hangs).
        if (t < 8) {
            int guard = 0;
            while (__hip_atomic_load(&flags[(x * 2 + z) * 8 + t],
                                     __ATOMIC_RELAXED,
                                     __HIP_MEMORY_SCOPE_AGENT) != SLAB_MAGIC) {
                __builtin_amdgcn_s_sleep(2);
                if (++guard > (1 << 20)) break;
            }
        }
        __syncthreads();
        // NO acquire fence: Xp/Yp reads below are agent-coherent loads that
        // bypass any stale local-L2 lines by construction.

        // Stage A (Xp/Yp f16) via coherent 8B loads.
        #pragma unroll 4
        for (int r = 0; r < 8; r++) {
            const int kt  = r * 32;
            const int m   = t >> 2;
            const int k8  = (t & 3) * 8;
            const int kp0 = r * 16 + (k8 >> 1);
            unsigned long long u0 = __hip_atomic_load(
                (const unsigned long long*)&A[(m0 + m) * 256 + kt + k8],
                __ATOMIC_RELAXED, __HIP_MEMORY_SCOPE_AGENT);
            unsigned long long u1 = __hip_atomic_load(
                (const unsigned long long*)&A[(m0 + m) * 256 + kt + k8 + 4],
                __ATOMIC_RELAXED, __HIP_MEMORY_SCOPE_AGENT);
            h4 v0, v1;
            __builtin_memcpy(&v0, &u0, 8);
            __builtin_memcpy(&v1, &u1, 8);
            h2 p0 = {v0[0], v0[1]}, p1 = {v0[2], v0[3]};
            h2 p2 = {v1[0], v1[1]}, p3 = {v1[2], v1[3]};
            *(h2*)&As2[(kp0 + 0) * 72 + 2 * m] = p0;
            *(h2*)&As2[(kp0 + 1) * 72 + 2 * m] = p1;
            *(h2*)&As2[(kp0 + 2) * 72 + 2 * m] = p2;
            *(h2*)&As2[(kp0 + 3) * 72 + 2 * m] = p3;
        }
        __syncthreads();

        float acc[4][4] = {};
        #pragma unroll 8
        for (int kp = 0; kp < 128; kp++) {
            h8 a = *(const h8*)&As2[kp * 72 + 8 * ti];
            h8 b = *(const h8*)&Bs2[kp * 136 + 8 * tj];
            const h2* ap = (const h2*)&a;
            const h2* bp = (const h2*)&b;
            #pragma unroll
            for (int mi = 0; mi < 4; mi++)
                #pragma unroll
                for (int nj = 0; nj < 4; nj++)
                    acc[mi][nj] = __builtin_amdgcn_fdot2(ap[mi], bp[nj],
                                                         acc[mi][nj], false);
        }

        float4 bv = {0.f, 0.f, 0.f, 0.f};
        if (bias) bv = *(const float4*)&bias[n0 + 4 * tj];
        #pragma unroll
        for (int mi = 0; mi < 4; mi++) {
            const int m = m0 + 4 * ti + mi;
            h4 r = {(_Float16)(acc[mi][0] + bv.x),
                    (_Float16)(acc[mi][1] + bv.y),
                    (_Float16)(acc[mi][2] + bv.z),
                    (_Float16)(acc[mi][3] + bv.w)};
            *(h4*)&Cc[m * 512 + n0 + 4 * tj] = r;
        }
    }
}

// ---------------------------------------------------------------------------
// Core: out[i,j] += sum_{h in 64-slab s} relu(hx[i,h]+hy[j,h])*w2[h]
// grid (8,8,8) = 512 blocks (2/CU), 256 threads, 4x4 register tile.
// f16 operands, v_dot2_f32_f16 accumulate. f32 atomicAdd epilogue into
// out (pre-filled with b2 by the fused kernel's producers).
// (proven R4/R5 body -- LDS ~6.9K cy vs VALU ~6.1K cy per CU, balanced)
// ---------------------------------------------------------------------------
__global__ __launch_bounds__(256) void affinity_core(
    const _Float16* __restrict__ hx, const _Float16* __restrict__ hy,
    const float* __restrict__ w2, float* __restrict__ out)
{
    __shared__ __align__(16) _Float16 xs[64 * 72];
    __shared__ __align__(16) _Float16 ys[64 * 72];
    __shared__ __align__(16) _Float16 ws2[64];

    const int t  = threadIdx.x;
    const int i0 = blockIdx.x * 64;
    const int j0 = blockIdx.y * 64;
    const int h0 = blockIdx.z * 64;
    const int ti = t / 16;
    const int tj = t % 16;

    #pragma unroll
    for (int s = 0; s < 2; s++) {
        const int id = t + s * 256;
        const int r  = id >> 3;
        const int c8 = (id & 7) * 8;
        *(float4*)&xs[r * 72 + c8] = *(const float4*)&hx[(i0 + r) * 512 + h0 + c8];
        *(float4*)&ys[r * 72 + c8] = *(const float4*)&hy[(j0 + r) * 512 + h0 + c8];
    }
    if (t < 64) ws2[t] = (_Float16)w2[h0 + t];
    __syncthreads();

    float acc[4][4] = {};
    const _Float16* xr = xs + ti * 72;
    const _Float16* yr = ys + tj * 72;
    const h2 hz = {(_Float16)0.f, (_Float16)0.f};

    #pragma unroll 2
    for (int g = 0; g < 8; g++) {
        const int ho = g * 8;
        h8 w = *(const h8*)&ws2[ho];
        h8 x[4], y[4];
        #pragma unroll
        for (int m = 0; m < 4; m++) x[m] = *(const h8*)&xr[m * (16 * 72) + ho];
        #pragma unroll
        for (int n = 0; n < 4; n++) y[n] = *(const h8*)&yr[n * (16 * 72) + ho];
        const h2* wp = (const h2*)&w;
        #pragma unroll
        for (int m = 0; m < 4; m++) {
            const h2* xp = (const h2*)&x[m];
            #pragma unroll
            for (int n = 0; n < 4; n++) {
                const h2* yp = (const h2*)&y[n];
                float a = acc[m][n];
                #pragma unroll
                for (int p = 0; p < 4; p++) {
                    h2 s = xp[p] + yp[p];                           // v_pk_add_f16
                    s = __builtin_elementwise_max(s, hz);           // v_pk_max_f16
                    a = __builtin_amdgcn_fdot2(s, wp[p], a, false); // v_dot2_f32_f16
                }
                acc[m][n] = a;
            }
        }
    }

    // Atomic f32 epilogue: 8-way contention per address (one per h-slab).
    #pragma unroll
    for (int m = 0; m < 4; m++) {
        #pragma unroll
        for (int n = 0; n < 4; n++) {
            atomicAdd(&out[(i0 + ti + 16 * m) * 512 + (j0 + tj + 16 * n)],
                      acc[m][n]);
        }
    }
}

extern "C" void kernel_launch(void* const* d_in, const int* in_sizes, int n_in,
                              void* d_out, int out_size, void* d_ws, size_t ws_size,
                              hipStream_t stream) {
    const float* X    = (const float*)d_in[0];  // 512x256
    const float* Y    = (const float*)d_in[1];  // 512x256
    const float* W_sr = (const float*)d_in[2];  // 256x256
    const float* W_tg = (const float*)d_in[3];  // 256x256
    const float* W1   = (const float*)d_in[4];  // 512x512 (H x 2C)
    const float* b1   = (const float*)d_in[5];  // 512
    const float* w2   = (const float*)d_in[6];  // 1x512
    const float* b2   = (const float*)d_in[7];  // 1

    float* ws = (float*)d_ws;
    _Float16* Xp = (_Float16*)ws;               // 512x256 f16
    _Float16* Yp = (_Float16*)(ws + 65536);     // 512x256 f16
    _Float16* hx = (_Float16*)(ws + 131072);    // 512x512 f16
    _Float16* hy = (_Float16*)(ws + 262144);    // 512x512 f16
    int* flags   = (int*)(ws + 393216);         // 256 ints (poisoned != MAGIC)
    float* out = (float*)d_out;

    // Stage 1+2 fused, zero fences: relaxed agent atomics for Xp/Yp + flags.
    fused_gemm12<<<512, 128, 0, stream>>>(
        X, Y, W_sr, W_tg, W1, b1, b2, Xp, Yp, hx, hy, out, flags);
    // Stage 3: h-split relu reduction, atomic f32 accumulate into out
    affinity_core<<<dim3(8, 8, 8), 256, 0, stream>>>(hx, hy, w2, out);
}

// Round 6
// 95.288 us; speedup vs baseline: 1.0790x; 1.0058x over previous
//
#include <hip/hip_runtime.h>

// Problem constants: N1=N2=512, C=256, H=512. Inputs/outputs fp32.
// M[i,j] = b2 + sum_h relu(hx[i,h] + hy[j,h] + b1[h]) * w2[h]
//   hx = (X @ W_sr.T) @ W1x.T, hy = (Y @ W_tg.T) @ W1y.T + b1.
//
// All stages move f16 data and accumulate fp32 via v_dot2_f32_f16.
// R3: grid.sync ~35us on gfx950 -- separate launches cheaper.
// R1: cap unrolls (full unroll -> 256 VGPR + scratch spills).
// R5: GEMMs LDS-pipe-bound; big per-thread tiles, 1 block/CU.
// R6: reduce8 -> atomicAdd epilogue (out prefilled with b2). 105.4->98.6.
// R8: full-K LDS staging, ONE barrier per GEMM. 98.6->94.9us (best).
//     ~80us harness poison-fill floor confirmed; pipeline ~14.5us.
// R9: fused gemm1+gemm2, agent release/acquire fences: +7.9us.
//     Lesson: block-granular TCC-wide wbl2/inv is ~10us of pure overhead.
// R10: same fusion, zero fences (relaxed agent atomics): 95.8us -- fence
//     cost gone but fusion nets ZERO vs R8: launch-gap saving (~2us) ==
//     spin + LLC-coherent-load + CU-sharing tax. Dependency chain is real;
//     in-kernel pipelining of sequential GEMMs does not pay on gfx950.
// R11 (this round): REVERT to R8 verbatim (best measured). Remaining
//     budget: ~80.4us fills (untouchable) + ~8.5us pipe-balanced kernels
//     + ~6us launch overhead (proven unrecoverable by R3/R9/R10).

typedef _Float16 h2 __attribute__((ext_vector_type(2)));
typedef _Float16 h4 __attribute__((ext_vector_type(4)));
typedef _Float16 h8 __attribute__((ext_vector_type(8)));

// ---------------------------------------------------------------------------
// GEMM-NT stage 1: Xp = X @ W_sr.T (and Y-path), f32 in -> f16 LDS, dot2,
// f16 out. M=512, N=256, K=256, lda=ldb=256. BM=32, BN=32, full K in LDS.
// 128 threads, per-thread 4 rows x 2 cols. LDS pair-major [kp][2m],
// stride 72 halfs. Single barrier. Also pre-fills out with b2.
// ---------------------------------------------------------------------------
__global__ __launch_bounds__(128) void gemm1_f16(
    const float* __restrict__ A0, const float* __restrict__ A1,
    const float* __restrict__ B0, const float* __restrict__ B1,
    _Float16* __restrict__ C0, _Float16* __restrict__ C1,
    const float* __restrict__ b2, float* __restrict__ out)
{
    const int z = blockIdx.z;
    const float* A = z ? A1 : A0;
    const float* B = z ? B1 : B0;
    _Float16* Cc   = z ? C1 : C0;

    __shared__ _Float16 As2[128 * 72];   // [kp=0..127][2m], 64 halfs used/row
    __shared__ _Float16 Bs2[128 * 72];   // [kp][2n]

    const int t  = threadIdx.x;
    const int m0 = blockIdx.x * 32;
    const int n0 = blockIdx.y * 32;
    const int ti = t >> 4;   // 0..7  -> rows 4ti..4ti+3
    const int tj = t & 15;   // 0..15 -> cols 2tj..2tj+1

    // out <- b2 (1024 floats per block; 8 per thread). Stream-ordered
    // before affinity_core's atomicAdd epilogue; re-runs on every graph
    // replay so the accumulation stays idempotent.
    {
        const int bid = blockIdx.x + 16 * (blockIdx.y + 8 * blockIdx.z);
        const float bb = b2[0];
        float4 f = {bb, bb, bb, bb};
        float* o = out + bid * 1024 + t * 8;
        *(float4*)o = f;
        *(float4*)(o + 4) = f;
    }

    // Stage ALL of K: 8 virtual k-tiles, proven per-tile mapping.
    #pragma unroll 4
    for (int r = 0; r < 8; r++) {
        const int kt = r * 32;
        #pragma unroll
        for (int s = 0; s < 2; s++) {
            const int id  = t + s * 128;
            const int m   = id >> 3;         // 0..31
            const int k4  = (id & 7) * 4;    // 0..28
            const int kp0 = r * 16 + (k4 >> 1);
            float4 va = *(const float4*)&A[(m0 + m) * 256 + kt + k4];
            h2 alo = {(_Float16)va.x, (_Float16)va.y};
            h2 ahi = {(_Float16)va.z, (_Float16)va.w};
            *(h2*)&As2[kp0 * 72 + 2 * m]       = alo;
            *(h2*)&As2[(kp0 + 1) * 72 + 2 * m] = ahi;
            float4 vb = *(const float4*)&B[(n0 + m) * 256 + kt + k4];
            h2 blo = {(_Float16)vb.x, (_Float16)vb.y};
            h2 bhi = {(_Float16)vb.z, (_Float16)vb.w};
            *(h2*)&Bs2[kp0 * 72 + 2 * m]       = blo;
            *(h2*)&Bs2[(kp0 + 1) * 72 + 2 * m] = bhi;
        }
    }
    __syncthreads();

    float acc[4][2] = {};
    #pragma unroll 8
    for (int kp = 0; kp < 128; kp++) {
        h8 a = *(const h8*)&As2[kp * 72 + 8 * ti];   // rows 4ti..4ti+3
        h4 b = *(const h4*)&Bs2[kp * 72 + 4 * tj];   // cols 2tj..2tj+1
        const h2* ap = (const h2*)&a;
        const h2* bp = (const h2*)&b;
        #pragma unroll
        for (int mi = 0; mi < 4; mi++)
            #pragma unroll
            for (int nj = 0; nj < 2; nj++)
                acc[mi][nj] = __builtin_amdgcn_fdot2(ap[mi], bp[nj],
                                                     acc[mi][nj], false);
    }

    #pragma unroll
    for (int mi = 0; mi < 4; mi++) {
        const int m = m0 + 4 * ti + mi;
        h2 r = {(_Float16)acc[mi][0], (_Float16)acc[mi][1]};
        *(h2*)&Cc[m * 256 + n0 + 2 * tj] = r;
    }
}

// ---------------------------------------------------------------------------
// GEMM-NT stage 2: hx = Xp @ W1x.T (+bias on y-path). A f16 (lda=256),
// B f32 (ldb=512, col offset prob*256) -> f16 LDS. M=512, N=512.
// BM=32, BN=64, full K in LDS (53KB). 128 threads, per-thread 4x4.
// As2 stride 72 halfs, Bs2 stride 136 halfs. Single barrier.
// ---------------------------------------------------------------------------
__global__ __launch_bounds__(128) void gemm2_f16(
    const _Float16* __restrict__ A0, const _Float16* __restrict__ A1,
    const float* __restrict__ B0, const float* __restrict__ B1,
    _Float16* __restrict__ C0, _Float16* __restrict__ C1,
    const float* __restrict__ bias1)
{
    const int z = blockIdx.z;
    const _Float16* A = z ? A1 : A0;
    const float* B    = z ? B1 : B0;
    _Float16* Cc      = z ? C1 : C0;
    const float* bias = z ? bias1 : nullptr;

    __shared__ _Float16 As2[128 * 72];    // [kp][2m], 64 halfs used
    __shared__ _Float16 Bs2[128 * 136];   // [kp][2n], 128 halfs used

    const int t  = threadIdx.x;
    const int m0 = blockIdx.x * 32;
    const int n0 = blockIdx.y * 64;
    const int ti = t >> 4;   // 0..7  -> rows 4ti..4ti+3
    const int tj = t & 15;   // 0..15 -> cols 4tj..4tj+3

    // Stage ALL of K.
    #pragma unroll 4
    for (int r = 0; r < 8; r++) {
        const int kt = r * 32;
        // A: 32m x 32k f16, 1 h8 per thread per tile
        {
            const int m   = t >> 2;          // 0..31
            const int k8  = (t & 3) * 8;     // 0..24
            const int kp0 = r * 16 + (k8 >> 1);
            h8 v = *(const h8*)&A[(m0 + m) * 256 + kt + k8];
            #pragma unroll
            for (int i = 0; i < 4; i++) {
                h2 p = {v[2 * i], v[2 * i + 1]};
                *(h2*)&As2[(kp0 + i) * 72 + 2 * m] = p;
            }
        }
        // B: 64n x 32k f32 -> f16, 4 float4 per thread per tile
        #pragma unroll
        for (int s = 0; s < 4; s++) {
            const int id  = t + s * 128;
            const int n   = id >> 3;         // 0..63
            const int k4  = (id & 7) * 4;
            const int kp0 = r * 16 + (k4 >> 1);
            float4 v = *(const float4*)&B[(n0 + n) * 512 + kt + k4];
            h2 lo = {(_Float16)v.x, (_Float16)v.y};
            h2 hi = {(_Float16)v.z, (_Float16)v.w};
            *(h2*)&Bs2[kp0 * 136 + 2 * n]       = lo;
            *(h2*)&Bs2[(kp0 + 1) * 136 + 2 * n] = hi;
        }
    }
    __syncthreads();

    float acc[4][4] = {};
    #pragma unroll 8
    for (int kp = 0; kp < 128; kp++) {
        h8 a = *(const h8*)&As2[kp * 72 + 8 * ti];
        h8 b = *(const h8*)&Bs2[kp * 136 + 8 * tj];
        const h2* ap = (const h2*)&a;
        const h2* bp = (const h2*)&b;
        #pragma unroll
        for (int mi = 0; mi < 4; mi++)
            #pragma unroll
            for (int nj = 0; nj < 4; nj++)
                acc[mi][nj] = __builtin_amdgcn_fdot2(ap[mi], bp[nj],
                                                     acc[mi][nj], false);
    }

    float4 bv = {0.f, 0.f, 0.f, 0.f};
    if (bias) bv = *(const float4*)&bias[n0 + 4 * tj];
    #pragma unroll
    for (int mi = 0; mi < 4; mi++) {
        const int m = m0 + 4 * ti + mi;
        h4 r = {(_Float16)(acc[mi][0] + bv.x), (_Float16)(acc[mi][1] + bv.y),
                (_Float16)(acc[mi][2] + bv.z), (_Float16)(acc[mi][3] + bv.w)};
        *(h4*)&Cc[m * 512 + n0 + 4 * tj] = r;
    }
}

// ---------------------------------------------------------------------------
// Core: out[i,j] += sum_{h in 64-slab s} relu(hx[i,h]+hy[j,h])*w2[h]
// grid (8,8,8) = 512 blocks (2/CU), 256 threads, 4x4 register tile.
// f16 operands, v_dot2_f32_f16 accumulate. f32 atomicAdd epilogue into
// out (pre-filled with b2 by gemm1).
// (proven R4/R5 body -- LDS ~6.9K cy vs VALU ~6.1K cy per CU, balanced)
// ---------------------------------------------------------------------------
__global__ __launch_bounds__(256) void affinity_core(
    const _Float16* __restrict__ hx, const _Float16* __restrict__ hy,
    const float* __restrict__ w2, float* __restrict__ out)
{
    __shared__ __align__(16) _Float16 xs[64 * 72];
    __shared__ __align__(16) _Float16 ys[64 * 72];
    __shared__ __align__(16) _Float16 ws2[64];

    const int t  = threadIdx.x;
    const int i0 = blockIdx.x * 64;
    const int j0 = blockIdx.y * 64;
    const int h0 = blockIdx.z * 64;
    const int ti = t / 16;
    const int tj = t % 16;

    #pragma unroll
    for (int s = 0; s < 2; s++) {
        const int id = t + s * 256;
        const int r  = id >> 3;
        const int c8 = (id & 7) * 8;
        *(float4*)&xs[r * 72 + c8] = *(const float4*)&hx[(i0 + r) * 512 + h0 + c8];
        *(float4*)&ys[r * 72 + c8] = *(const float4*)&hy[(j0 + r) * 512 + h0 + c8];
    }
    if (t < 64) ws2[t] = (_Float16)w2[h0 + t];
    __syncthreads();

    float acc[4][4] = {};
    const _Float16* xr = xs + ti * 72;
    const _Float16* yr = ys + tj * 72;
    const h2 hz = {(_Float16)0.f, (_Float16)0.f};

    #pragma unroll 2
    for (int g = 0; g < 8; g++) {
        const int ho = g * 8;
        h8 w = *(const h8*)&ws2[ho];
        h8 x[4], y[4];
        #pragma unroll
        for (int m = 0; m < 4; m++) x[m] = *(const h8*)&xr[m * (16 * 72) + ho];
        #pragma unroll
        for (int n = 0; n < 4; n++) y[n] = *(const h8*)&yr[n * (16 * 72) + ho];
        const h2* wp = (const h2*)&w;
        #pragma unroll
        for (int m = 0; m < 4; m++) {
            const h2* xp = (const h2*)&x[m];
            #pragma unroll
            for (int n = 0; n < 4; n++) {
                const h2* yp = (const h2*)&y[n];
                float a = acc[m][n];
                #pragma unroll
                for (int p = 0; p < 4; p++) {
                    h2 s = xp[p] + yp[p];                           // v_pk_add_f16
                    s = __builtin_elementwise_max(s, hz);           // v_pk_max_f16
                    a = __builtin_amdgcn_fdot2(s, wp[p], a, false); // v_dot2_f32_f16
                }
                acc[m][n] = a;
            }
        }
    }

    // Atomic f32 epilogue: 8-way contention per address (one per h-slab),
    // 2M atomics total -- well within L2 atomic throughput.
    #pragma unroll
    for (int m = 0; m < 4; m++) {
        #pragma unroll
        for (int n = 0; n < 4; n++) {
            atomicAdd(&out[(i0 + ti + 16 * m) * 512 + (j0 + tj + 16 * n)],
                      acc[m][n]);
        }
    }
}

extern "C" void kernel_launch(void* const* d_in, const int* in_sizes, int n_in,
                              void* d_out, int out_size, void* d_ws, size_t ws_size,
                              hipStream_t stream) {
    const float* X    = (const float*)d_in[0];  // 512x256
    const float* Y    = (const float*)d_in[1];  // 512x256
    const float* W_sr = (const float*)d_in[2];  // 256x256
    const float* W_tg = (const float*)d_in[3];  // 256x256
    const float* W1   = (const float*)d_in[4];  // 512x512 (H x 2C)
    const float* b1   = (const float*)d_in[5];  // 512
    const float* w2   = (const float*)d_in[6];  // 1x512
    const float* b2   = (const float*)d_in[7];  // 1

    float* ws = (float*)d_ws;
    _Float16* Xp = (_Float16*)ws;               // 512x256 f16
    _Float16* Yp = (_Float16*)(ws + 65536);     // 512x256 f16
    _Float16* hx = (_Float16*)(ws + 131072);    // 512x512 f16
    _Float16* hy = (_Float16*)(ws + 262144);    // 512x512 f16
    float* out = (float*)d_out;

    // Stage 1: Xp = X @ W_sr.T ; Yp = Y @ W_tg.T ; out <- b2
    gemm1_f16<<<dim3(16, 8, 2), 128, 0, stream>>>(
        X, Y, W_sr, W_tg, Xp, Yp, b2, out);
    // Stage 2: hx = Xp @ W1x.T ; hy = Yp @ W1y.T + b1
    gemm2_f16<<<dim3(16, 8, 2), 128, 0, stream>>>(
        Xp, Yp, W1, W1 + 256, hx, hy, b1);
    // Stage 3: h-split relu reduction, atomic f32 accumulate into out
    affinity_core<<<dim3(8, 8, 8), 256, 0, stream>>>(hx, hy, w2, out);
}